// Round 6
// baseline (170.644 us; speedup 1.0000x reference)
//
#include <hip/hip_runtime.h>
#include <hip/hip_bf16.h>

// B=64,C=4 -> BF=256, N=1024, G=32, D=3, K=512
#define BFN   256
#define NPTS  1024
#define KSEL  512
#define GD    96          // G*D floats per patch row
#define ROW4  24          // GD/4 float4s per patch row (384 B)

typedef unsigned long long u64;

// Fused: per-bf sort (regs/LDS) -> rank table in LDS -> stream-read gather.
// One launch, no workspace traffic.
__global__ __launch_bounds__(1024)
void crop_fused_kernel(const float*  __restrict__ centers,
                       const float4* __restrict__ patches4,
                       const int*    __restrict__ center_idx,
                       float4* __restrict__ out_p4,
                       float*  __restrict__ out_c)
{
    __shared__ u64 keys[NPTS];
    __shared__ int rank_s[NPTS];

    const int bf = blockIdx.x;
    const int t  = threadIdx.x;

    rank_s[t] = -1;

    const float* cbase = centers + (size_t)bf * NPTS * 3;
    const int qi = center_idx[bf];
    const float q0 = cbase[qi * 3 + 0], q1 = cbase[qi * 3 + 1], q2 = cbase[qi * 3 + 2];
    const float c0 = cbase[t * 3 + 0],  c1 = cbase[t * 3 + 1],  c2 = cbase[t * 3 + 2];

    // f64 d2 from f32 inputs is exact -> true ordering, matches numpy ref
    // (round-3 verified: absmax 0.0).
    const double e0 = (double)q0 - (double)c0;
    const double e1 = (double)q1 - (double)c1;
    const double e2 = (double)q2 - (double)c2;
    const double d2 = e0 * e0 + e1 * e1 + e2 * e2;

    // d2>=0 -> f64 bits monotone; low 10 bits = index (stable tie-break).
    u64 key = (((u64)__double_as_longlong(d2)) & ~0x3FFull) | (u64)t;

    // bitonic sort: strides<=32 in-wave shfl (no barrier), strides>=64 via LDS.
    for (int size = 2; size <= NPTS; size <<= 1) {
        const bool dir = (t & size) != 0;
        for (int stride = size >> 1; stride > 0; stride >>= 1) {
            u64 other;
            if (stride >= 64) {
                __syncthreads();
                keys[t] = key;
                __syncthreads();
                other = keys[t ^ stride];
            } else {
                other = __shfl_xor(key, stride, 64);
            }
            const bool upper    = (t & stride) != 0;
            const bool keep_min = (upper == dir);
            const bool mine_lt  = key < other;       // keys unique
            key = (keep_min == mine_lt) ? key : other;
        }
    }
    __syncthreads();   // covers rank_s init too

    if (t < KSEL) {
        const int idx = (int)(key & 0x3FFull);
        rank_s[idx] = t;                         // inverse permutation, in LDS
        // centers: 12KB tile is L1-hot from the distance reads; write 12B/row
        const float* cs = cbase + (size_t)idx * 3;
        float* oc = out_c + ((size_t)bf * KSEL + t) * 3;
        oc[0] = cs[0]; oc[1] = cs[1]; oc[2] = cs[2];
    }
    __syncthreads();

    // stream-read this bf's full patch tile (384KB, coalesced), scatter-write
    // selected rows by rank into the 196KB output window (L2-absorbed).
    const float4* src = patches4 + (size_t)bf * NPTS * ROW4;
    float4*       dst = out_p4   + (size_t)bf * KSEL * ROW4;

    #pragma unroll
    for (int it = 0; it < 24; ++it) {
        const int flat = it * 1024 + t;          // [0, 24576) = 1024 rows * 24
        const float4 v = src[flat];              // sequential across block
        const int row  = flat / 24;              // const-divisor -> magic mul
        const int lane = flat - row * 24;
        const int r    = rank_s[row];
        if (r >= 0) dst[(size_t)r * ROW4 + lane] = v;
    }
}

extern "C" void kernel_launch(void* const* d_in, const int* in_sizes, int n_in,
                              void* d_out, int out_size, void* d_ws, size_t ws_size,
                              hipStream_t stream)
{
    const float* patches    = (const float*)d_in[0];
    const float* centers    = (const float*)d_in[1];
    const int*   center_idx = (const int*)d_in[2];
    // d_in[3] is K (=512), static; hardcoded as KSEL.

    float* out_patches = (float*)d_out;                           // BF*K*G*D
    float* out_centers = (float*)d_out + (size_t)BFN * KSEL * GD; // BF*K*D

    crop_fused_kernel<<<BFN, 1024, 0, stream>>>(centers, (const float4*)patches,
                                                center_idx, (float4*)out_patches,
                                                out_centers);
}